// Round 4
// baseline (471.642 us; speedup 1.0000x reference)
//
#include <hip/hip_runtime.h>

// B=128, C_IN=128, C_HID=256, C_OUT=128, H*W=1600, E=8, TOP_K=2.
#define CIN   128
#define CHID  256
#define COUT  128
#define HWPX  1600
#define NT    50      // 32-px tiles per batch image
#define TPX   32

typedef __attribute__((ext_vector_type(8))) short bf16x8;  // 8 bf16 = 4 VGPRs
typedef __attribute__((ext_vector_type(4))) float f32x4;   // MFMA C/D

__device__ __forceinline__ unsigned short f2bf(float f) {
  unsigned int u = __builtin_bit_cast(unsigned int, f);
  u += 0x7FFFu + ((u >> 16) & 1u);
  return (unsigned short)(u >> 16);
}
__device__ __forceinline__ unsigned int pack_bf2(float a, float b) {
  return (unsigned int)f2bf(a) | ((unsigned int)f2bf(b) << 16);
}
// Fast SiLU: v_exp_f32 + v_rcp_f32 (~1e-7 rel err, invisible under bf16).
__device__ __forceinline__ unsigned int silu_gate_pk(float a, float b, float g) {
  const float ea = __builtin_amdgcn_exp2f(a * -1.442695041f);
  const float eb = __builtin_amdgcn_exp2f(b * -1.442695041f);
  const float sa = g * a * __builtin_amdgcn_rcpf(1.0f + ea);
  const float sb = g * b * __builtin_amdgcn_rcpf(1.0f + eb);
  return pack_bf2(sa, sb);
}

// Async 8 KB tile stage: 8 x global_load_lds_dwordx4.
// LDS dest is wave-uniform base + lane*16; global src is per-lane.
__device__ __forceinline__ void stage_tile(const unsigned short* g,
                                           unsigned short* l, int lane) {
#pragma unroll
  for (int k = 0; k < 8; ++k)
    __builtin_amdgcn_global_load_lds(
        (const __attribute__((address_space(1))) unsigned int*)(g + (k * 64 + lane) * 8),
        (__attribute__((address_space(3))) unsigned int*)(l + k * 512),
        16, 0, 0);
}

// ---------------------------------------------------------------------------
// Combined converter.
//  x part (do_x=1, blocks [0,1664)): fp32 x -> bf16 tile images in the exact
//    LDS layout (incl. rotation slot=(chunk+px)&15): xbf[(b*50+t)*4096 + ...]
//  W part (last 1024 blocks): per-instruction-order fragments (as before).
//   W1c: ((e*8+grp)*8 + ks*2 + half)*64 + lane, row ch = grp*32 +
//        ((r16>>2)<<3)+(r16&3)+(half<<2), cin chunk = ks*4+q.
//   W2c: ((e*8+grp)*8 + mt)*64 + lane, row co = mt*16+r16, ch = grp*32+q*8+j.
// ---------------------------------------------------------------------------
__global__ __launch_bounds__(256) void convert_kernel(
    const float* __restrict__ x, const float* __restrict__ W1,
    const float* __restrict__ W2, unsigned short* __restrict__ W1c,
    unsigned short* __restrict__ W2c, unsigned short* __restrict__ xbf,
    int do_x) {
  __shared__ __align__(16) unsigned short xl[4][4096];
  const int bid = blockIdx.x;
  if (do_x && bid < 1664) {
    const int wave = threadIdx.x >> 6, lane = threadIdx.x & 63;
    const int b = bid / 13, blk = bid % 13;
    const int tile = blk * 4 + wave;
    if (tile >= NT) return;
    const int p = lane & 31, h = lane >> 5;
    const float* xr = x + (long)b * CIN * HWPX + tile * TPX + p;
    unsigned short* w = &xl[wave][0];
#pragma unroll
    for (int c = 0; c < 8; ++c) {
      const int cc = c * 2 + h;               // cin chunk 0..15
      float v[8];
#pragma unroll
      for (int jj = 0; jj < 8; ++jj) v[jj] = xr[(long)(cc * 8 + jj) * HWPX];
      union { bf16x8 t; unsigned int u[4]; } t;
#pragma unroll
      for (int d = 0; d < 4; ++d) t.u[d] = pack_bf2(v[2 * d], v[2 * d + 1]);
      const int slot = (cc + p) & 15;         // rotation (bank spread)
      *reinterpret_cast<bf16x8*>(&w[(p * 16 + slot) * 8]) = t.t;
    }
    // linear flush (wave-internal DS FIFO -> no barrier), coalesced 1 KB stores
    uint4* dst = reinterpret_cast<uint4*>(xbf + ((long)b * NT + tile) * 4096);
    const uint4* src = reinterpret_cast<const uint4*>(w);
#pragma unroll
    for (int k = 0; k < 8; ++k) dst[k * 64 + lane] = src[k * 64 + lane];
    return;
  }
  const int wb = do_x ? (bid - 1664) : bid;
  if (wb >= 1024) return;
  const int i    = wb * 256 + threadIdx.x;    // 0 .. 262143
  const int j    = i & 7;
  const int lane = (i >> 3) & 63;
  const int r16  = lane & 15;
  const int q    = lane >> 4;
  {
    const int half = (i >> 9) & 1;
    const int ks   = (i >> 10) & 3;
    const int grp  = (i >> 12) & 7;
    const int e    = i >> 15;
    const int ch   = grp * 32 + ((r16 >> 2) << 3) + (r16 & 3) + (half << 2);
    const int c    = ks * 4 + q;
    W1c[i] = f2bf(W1[(e * CHID + ch) * CIN + c * 8 + j]);
  }
  {
    const int mt  = (i >> 9) & 7;
    const int grp = (i >> 12) & 7;
    const int e   = i >> 15;
    const int co  = mt * 16 + r16;
    W2c[i] = f2bf(W2[(e * COUT + co) * CHID + grp * 32 + q * 8 + j]);
  }
}

// ---------------------------------------------------------------------------
// moe v3: 32-px tiles, 3-4 tiles per wave, double-buffered async LDS staging.
// Grid 128*4 = 512 blocks = exactly 2 blocks/CU (single residency round).
// No barriers anywhere; per-wave private LDS (2 x 8 KB dbuf).
// ---------------------------------------------------------------------------
__global__ __launch_bounds__(256, 2) void moe_kernel_v3(
    const unsigned short* __restrict__ xbf, const float* __restrict__ wts,
    const int* __restrict__ idx, const unsigned short* __restrict__ W1,
    const float* __restrict__ b1, const unsigned short* __restrict__ W2,
    const float* __restrict__ b2, float* __restrict__ out) {
  __shared__ __align__(16) unsigned short lds[4][2][4096];   // 64 KB

  const int tid  = threadIdx.x;
  const int wave = tid >> 6;
  const int lane = tid & 63;
  const int q    = lane >> 4;
  const int r16  = lane & 15;

  const int b    = blockIdx.x >> 2;
  const int slot = (blockIdx.x & 3) * 4 + wave;   // 0..15 wave-slot within b
  const int n    = (slot < 2) ? 4 : 3;            // tiles: slot + 16*i

  const int   e0 = __builtin_amdgcn_readfirstlane(idx[b * 2 + 0]);
  const int   e1 = __builtin_amdgcn_readfirstlane(idx[b * 2 + 1]);
  const float g0 = wts[b * 2 + 0], g1 = wts[b * 2 + 1];

  const unsigned short* xb = xbf + (long)b * NT * 4096;
  const int lane8 = lane * 8;

  // issue stage of first tile
  stage_tile(xb + (long)slot * 4096, &lds[wave][0][0], lane);

  for (int i = 0; i < n; ++i) {
    // drain this tile's staging loads (and any stale weight loads/stores)
    asm volatile("s_waitcnt vmcnt(0)" ::: "memory");
    __builtin_amdgcn_sched_barrier(0);
    // issue next tile's staging into the other buffer; flies under compute
    if (i + 1 < n)
      stage_tile(xb + (long)(slot + 16 * (i + 1)) * 4096,
                 &lds[wave][(i + 1) & 1][0], lane);

    unsigned short* xw = &lds[wave][i & 1][0];

    f32x4 accO[8][2];
#pragma unroll
    for (int mt = 0; mt < 8; ++mt)
#pragma unroll
      for (int nt = 0; nt < 2; ++nt) accO[mt][nt] = (f32x4){0.f, 0.f, 0.f, 0.f};

#pragma unroll
    for (int gs = 0; gs < 16; ++gs) {
      const int   sl  = gs >> 3;
      const int   grp = gs & 7;
      const int   e   = sl ? e1 : e0;
      const float g   = sl ? g1 : g0;
      const unsigned short* w1s = W1 + ((long)(e * 8 + grp) << 12);
      const unsigned short* w2s = W2 + ((long)(e * 8 + grp) << 12);

      // GEMM1: 32 hidden ch (permuted rows), K = 128
      f32x4 aA[2], aB[2];
#pragma unroll
      for (int nt = 0; nt < 2; ++nt) {
        aA[nt] = (f32x4){0.f, 0.f, 0.f, 0.f};
        aB[nt] = (f32x4){0.f, 0.f, 0.f, 0.f};
      }
#pragma unroll
      for (int ks = 0; ks < 4; ++ks) {
        const bf16x8 w0 = *reinterpret_cast<const bf16x8*>(
            &w1s[(ks * 2 + 0) * 512 + lane8]);
        const bf16x8 w1v = *reinterpret_cast<const bf16x8*>(
            &w1s[(ks * 2 + 1) * 512 + lane8]);
#pragma unroll
        for (int nt = 0; nt < 2; ++nt) {
          const int px = nt * 16 + r16;
          const bf16x8 xf = *reinterpret_cast<const bf16x8*>(
              &xw[(px * 16 + ((ks * 4 + q + px) & 15)) * 8]);
          aA[nt] = __builtin_amdgcn_mfma_f32_16x16x32_bf16(w0, xf, aA[nt], 0, 0, 0);
          aB[nt] = __builtin_amdgcn_mfma_f32_16x16x32_bf16(w1v, xf, aB[nt], 0, 0, 0);
        }
      }

      // bias + SiLU + gate -> GEMM2 B-fragments (true ch = base + q*8 + j)
      const float* b1e = b1 + e * CHID + grp * 32;
      const f32x4 bA = *reinterpret_cast<const f32x4*>(&b1e[q * 8]);
      const f32x4 bB = *reinterpret_cast<const f32x4*>(&b1e[q * 8 + 4]);
      union { bf16x8 v; unsigned int u[4]; } h[2];
#pragma unroll
      for (int nt = 0; nt < 2; ++nt) {
        h[nt].u[0] = silu_gate_pk(aA[nt][0] + bA[0], aA[nt][1] + bA[1], g);
        h[nt].u[1] = silu_gate_pk(aA[nt][2] + bA[2], aA[nt][3] + bA[3], g);
        h[nt].u[2] = silu_gate_pk(aB[nt][0] + bB[0], aB[nt][1] + bB[1], g);
        h[nt].u[3] = silu_gate_pk(aB[nt][2] + bB[2], aB[nt][3] + bB[3], g);
      }

      // GEMM2 partial-K (this 32-ch chunk)
#pragma unroll
      for (int mt = 0; mt < 8; ++mt) {
        const bf16x8 w2v = *reinterpret_cast<const bf16x8*>(
            &w2s[mt * 512 + lane8]);
#pragma unroll
        for (int nt = 0; nt < 2; ++nt)
          accO[mt][nt] = __builtin_amdgcn_mfma_f32_16x16x32_bf16(w2v, h[nt].v, accO[mt][nt], 0, 0, 0);
      }
    }

    // epilogue: transpose via dead x buffer (wave-internal DS FIFO), then
    // coalesced 16 B stores. 16 rows x 36 floats = 2304 B <= 8 KB.
    float* eb = reinterpret_cast<float*>(xw);
    const float* b2e0 = b2 + e0 * COUT;
    const float* b2e1 = b2 + e1 * COUT;
    const int  coR  = lane >> 2;
    const int  qtr  = lane & 3;
    const long px0  = (long)(slot + 16 * i) * TPX;
    const long obase = (long)b * COUT * HWPX + px0;
#pragma unroll
    for (int mt = 0; mt < 8; ++mt) {
      const int coW = q * 4;
      const f32x4 bias = g0 * (*reinterpret_cast<const f32x4*>(&b2e0[mt * 16 + coW])) +
                         g1 * (*reinterpret_cast<const f32x4*>(&b2e1[mt * 16 + coW]));
#pragma unroll
      for (int nt = 0; nt < 2; ++nt) {
        const f32x4 v = accO[mt][nt] + bias;
#pragma unroll
        for (int rr = 0; rr < 4; ++rr)
          eb[(coW + rr) * 36 + nt * 16 + r16] = v[rr];
      }
      const long orow = obase + (long)(mt * 16 + coR) * HWPX;
#pragma unroll
      for (int k = 0; k < 2; ++k) {
        const float4 ov = *reinterpret_cast<const float4*>(
            &eb[coR * 36 + k * 16 + qtr * 4]);
        *reinterpret_cast<float4*>(&out[orow + k * 16 + qtr * 4]) = ov;
      }
    }
  }
}

// ---------------------------------------------------------------------------
// Fallback (verified round-2 kernel) if workspace is too small for xbf.
// ---------------------------------------------------------------------------
__global__ __launch_bounds__(256, 2) void moe_kernel_v2(
    const float* __restrict__ x, const float* __restrict__ wts,
    const int* __restrict__ idx, const unsigned short* __restrict__ W1,
    const float* __restrict__ b1, const unsigned short* __restrict__ W2,
    const float* __restrict__ b2, float* __restrict__ out) {
  __shared__ __align__(16) unsigned short lds[32768];
  const int tid  = threadIdx.x;
  const int wave = tid >> 6;
  const int lane = tid & 63;
  const int q    = lane >> 4;
  const int r16  = lane & 15;
  const int  b    = blockIdx.x / 7;
  const int  t4   = blockIdx.x % 7;
  const int  tile = t4 * 4 + wave;
  if (tile >= 25) return;
  const int  px0  = tile * 64;
  unsigned short* xw = &lds[wave * 8192];
  {
    const float* xb = x + (long)b * CIN * HWPX + px0 + lane;
#pragma unroll 4
    for (int c = 0; c < 16; ++c) {
      float v[8];
#pragma unroll
      for (int jj = 0; jj < 8; ++jj) v[jj] = xb[(long)(c * 8 + jj) * HWPX];
      union { bf16x8 w; unsigned int u[4]; } t;
#pragma unroll
      for (int d = 0; d < 4; ++d) t.u[d] = pack_bf2(v[2 * d], v[2 * d + 1]);
      const int slot = (c + lane) & 15;
      *reinterpret_cast<bf16x8*>(&xw[(lane * 16 + slot) * 8]) = t.w;
    }
  }
  const int   e0 = __builtin_amdgcn_readfirstlane(idx[b * 2 + 0]);
  const int   e1 = __builtin_amdgcn_readfirstlane(idx[b * 2 + 1]);
  const float g0 = wts[b * 2 + 0], g1 = wts[b * 2 + 1];
  f32x4 accO[8][4];
#pragma unroll
  for (int mt = 0; mt < 8; ++mt)
#pragma unroll
    for (int nt = 0; nt < 4; ++nt) accO[mt][nt] = (f32x4){0.f, 0.f, 0.f, 0.f};
  const int lane8 = lane * 8;
  for (int gs = 0; gs < 16; ++gs) {
    const int   sl  = gs >> 3;
    const int   grp = gs & 7;
    const int   e   = sl ? e1 : e0;
    const float g   = sl ? g1 : g0;
    const unsigned short* w1s = W1 + ((long)(e * 8 + grp) << 12);
    const unsigned short* w2s = W2 + ((long)(e * 8 + grp) << 12);
    f32x4 aA[4], aB[4];
#pragma unroll
    for (int nt = 0; nt < 4; ++nt) {
      aA[nt] = (f32x4){0.f, 0.f, 0.f, 0.f};
      aB[nt] = (f32x4){0.f, 0.f, 0.f, 0.f};
    }
#pragma unroll
    for (int ks = 0; ks < 4; ++ks) {
      const bf16x8 w0 = *reinterpret_cast<const bf16x8*>(
          &w1s[(ks * 2 + 0) * 512 + lane8]);
      const bf16x8 w1v = *reinterpret_cast<const bf16x8*>(
          &w1s[(ks * 2 + 1) * 512 + lane8]);
#pragma unroll
      for (int nt = 0; nt < 4; ++nt) {
        const int px = nt * 16 + r16;
        const bf16x8 xf = *reinterpret_cast<const bf16x8*>(
            &xw[(px * 16 + ((ks * 4 + q + px) & 15)) * 8]);
        aA[nt] = __builtin_amdgcn_mfma_f32_16x16x32_bf16(w0, xf, aA[nt], 0, 0, 0);
        aB[nt] = __builtin_amdgcn_mfma_f32_16x16x32_bf16(w1v, xf, aB[nt], 0, 0, 0);
      }
    }
    const float* b1e = b1 + e * CHID + grp * 32;
    const f32x4 bA = *reinterpret_cast<const f32x4*>(&b1e[q * 8]);
    const f32x4 bB = *reinterpret_cast<const f32x4*>(&b1e[q * 8 + 4]);
    union { bf16x8 v; unsigned int u[4]; } h[4];
#pragma unroll
    for (int nt = 0; nt < 4; ++nt) {
      h[nt].u[0] = silu_gate_pk(aA[nt][0] + bA[0], aA[nt][1] + bA[1], g);
      h[nt].u[1] = silu_gate_pk(aA[nt][2] + bA[2], aA[nt][3] + bA[3], g);
      h[nt].u[2] = silu_gate_pk(aB[nt][0] + bB[0], aB[nt][1] + bB[1], g);
      h[nt].u[3] = silu_gate_pk(aB[nt][2] + bB[2], aB[nt][3] + bB[3], g);
    }
#pragma unroll
    for (int mt = 0; mt < 8; ++mt) {
      const bf16x8 w2v = *reinterpret_cast<const bf16x8*>(
          &w2s[mt * 512 + lane8]);
#pragma unroll
      for (int nt = 0; nt < 4; ++nt)
        accO[mt][nt] = __builtin_amdgcn_mfma_f32_16x16x32_bf16(w2v, h[nt].v, accO[mt][nt], 0, 0, 0);
    }
  }
  float* eb = reinterpret_cast<float*>(xw);
  const float* b2e0 = b2 + e0 * COUT;
  const float* b2e1 = b2 + e1 * COUT;
  const int  coR   = lane >> 2;
  const int  qtr   = lane & 3;
  const long orow0 = (long)b * COUT * HWPX + px0 + qtr * 16;
#pragma unroll
  for (int mt = 0; mt < 8; ++mt) {
    const int coW = q * 4;
    const f32x4 bias = g0 * (*reinterpret_cast<const f32x4*>(&b2e0[mt * 16 + coW])) +
                       g1 * (*reinterpret_cast<const f32x4*>(&b2e1[mt * 16 + coW]));
#pragma unroll
    for (int nt = 0; nt < 4; ++nt) {
      const f32x4 v = accO[mt][nt] + bias;
#pragma unroll
      for (int rr = 0; rr < 4; ++rr)
        eb[(coW + rr) * 68 + nt * 16 + r16] = v[rr];
    }
    {
      const long orow = orow0 + (long)(mt * 16 + coR) * HWPX;
#pragma unroll
      for (int i4 = 0; i4 < 4; ++i4) {
        const float4 ov = *reinterpret_cast<const float4*>(
            &eb[coR * 68 + qtr * 16 + i4 * 4]);
        *reinterpret_cast<float4*>(&out[orow + i4 * 4]) = ov;
      }
    }
  }
}

extern "C" void kernel_launch(void* const* d_in, const int* in_sizes, int n_in,
                              void* d_out, int out_size, void* d_ws, size_t ws_size,
                              hipStream_t stream) {
  const float* x   = (const float*)d_in[0];
  const float* wts = (const float*)d_in[1];
  const int*   idx = (const int*)d_in[2];
  const float* W1  = (const float*)d_in[3];
  const float* b1  = (const float*)d_in[4];
  const float* W2  = (const float*)d_in[5];
  const float* b2  = (const float*)d_in[6];
  float* out = (float*)d_out;

  unsigned short* W1c = (unsigned short*)d_ws;            // 262144 shorts
  unsigned short* W2c = W1c + 8 * CHID * CIN;             // 262144 shorts
  unsigned short* xbf = W2c + 8 * CHID * CIN;             // 128*50*4096 shorts

  const size_t need = (size_t)2 * 8 * CHID * CIN * 2 +
                      (size_t)128 * NT * 4096 * 2;        // ~54.5 MB
  if (ws_size >= need) {
    convert_kernel<<<1664 + 1024, 256, 0, stream>>>(x, W1, W2, W1c, W2c, xbf, 1);
    moe_kernel_v3<<<128 * 4, 256, 0, stream>>>(xbf, wts, idx, W1c, b1, W2c, b2, out);
  } else {
    convert_kernel<<<1024, 256, 0, stream>>>(x, W1, W2, W1c, W2c, xbf, 0);
    moe_kernel_v2<<<128 * 7, 256, 0, stream>>>(x, wts, idx, W1c, b1, W2c, b2, out);
  }
}